// Round 5
// baseline (327.656 us; speedup 1.0000x reference)
//
#include <hip/hip_runtime.h>
#include <math.h>

#define NBINS 256
#define TPB 128   // threads/block. Private uint16 histogram per thread:
                  // lh[bin][tid], 256*128*2B = 64 KB LDS -> 2 blocks/CU.
                  // Each lane RMWs ONLY its own column -> race-free with
                  // plain ds_read/ds_write (no atomics). Bank = (tid>>1)&31
                  // (bin*256B stride == 0 mod 32 banks) -> conflict-free.
// WHY: r0-r4 evidence: time invariant to HBM/L3 residency, access pattern,
// MLP, occupancy, and bank conflicts (r4: SQ_LDS_BANK_CONFLICT 2.46M -> 0,
// dur unchanged). 262k elements/CU == 248k cycles == ~1 elem/cy/CU: the
// per-CU LDS ATOMIC unit is the serial resource. Fix = no atomics at all.

// torch.histc semantics over [-1,1], 256 bins: floor((x+1)*128) (exact:
// (x+1) rounds, *128=*2^7 exact), clip to 255, ignore out-of-range.
// Out-of-range lanes clamp to bin 0 with increment 0 (harmless write-back
// of the pre-value into the lane's OWN column; duplicate logic keeps it
// consistent with valid bin-0 hits in the same group).

__device__ __forceinline__ void procgrp(float4 v, unsigned short* __restrict__ lh,
                                        int tid) {
    float vv[4] = {v.x, v.y, v.z, v.w};
    int bn[4], val[4], idx[4];
#pragma unroll
    for (int j = 0; j < 4; j++) {
        float f = vv[j];
        int ok = (f >= -1.0f) & (f <= 1.0f);
        int bb = (int)((f + 1.0f) * 128.0f);       // trunc == floor (f+1 >= 0)
        bb = bb > (NBINS - 1) ? (NBINS - 1) : bb;  // f == 1.0 -> last bin
        bn[j] = ok ? bb : 0;
        val[j] = ok;
        idx[j] = (bn[j] << 7) + tid;               // lh[bin][tid], TPB=128
    }
    // 4 independent reads issue back-to-back (4x latency amortization);
    // compiler cannot sink writes above possibly-aliasing reads, so the
    // r0..r3 / w0..w3 grouping is preserved.
    unsigned short r0 = lh[idx[0]];
    unsigned short r1 = lh[idx[1]];
    unsigned short r2 = lh[idx[2]];
    unsigned short r3 = lh[idx[3]];
    // Duplicate-aware increments: inc_j = valid_j + sum_{k<j}(valid_k && bk==bj).
    // HW keeps same-wave DS order, so the LAST writer of a duplicated bin
    // carries the full multiplicity -> last-write-wins is correct.
    int inc0 = val[0];
    int inc1 = val[1] + ((bn[0] == bn[1]) & val[0]);
    int inc2 = val[2] + ((bn[0] == bn[2]) & val[0]) + ((bn[1] == bn[2]) & val[1]);
    int inc3 = val[3] + ((bn[0] == bn[3]) & val[0]) + ((bn[1] == bn[3]) & val[1])
                      + ((bn[2] == bn[3]) & val[2]);
    lh[idx[0]] = (unsigned short)(r0 + inc0);
    lh[idx[1]] = (unsigned short)(r1 + inc1);
    lh[idx[2]] = (unsigned short)(r2 + inc2);
    lh[idx[3]] = (unsigned short)(r3 + inc3);
}

__global__ __launch_bounds__(TPB) void hist2_kernel(const float* __restrict__ a,
                                                    const float* __restrict__ b,
                                                    unsigned int* __restrict__ ghist,
                                                    int n4a, int n4b, int half_blocks) {
    __shared__ unsigned short lh[NBINS * TPB];  // 64 KB
    const int tid = threadIdx.x;

    {   // zero 64 KB: 4096 uint4 / 128 threads = 32 per thread
        uint4* p = (uint4*)lh;
#pragma unroll
        for (int k = 0; k < 32; k++) p[k * TPB + tid] = make_uint4(0u, 0u, 0u, 0u);
    }
    __syncthreads();

    const int which = (blockIdx.x >= half_blocks) ? 1 : 0;
    const float4* __restrict__ x4 = (const float4*)(which ? b : a);
    const int n4 = which ? n4b : n4a;
    const int bid = which ? (blockIdx.x - half_blocks) : blockIdx.x;

    // Contiguous chunk per block (16384 float4 = 256 KB), swept in 2 KB steps.
    const int chunk = (n4 + half_blocks - 1) / half_blocks;
    const int beg = bid * chunk;
    const int end = (beg + chunk < n4) ? (beg + chunk) : n4;

    // Max per-counter count = elements/thread = 512 << 65535 (uint16 safe,
    // data-independent).
    int i = beg + tid;
    for (; i + TPB < end; i += 2 * TPB) {
        float4 v0 = x4[i];          // both loads issue before the RMW chains
        float4 v1 = x4[i + TPB];    // (global<->LDS don't alias)
        procgrp(v0, lh, tid);
        procgrp(v1, lh, tid);
    }
    for (; i < end; i += TPB) procgrp(x4[i], lh, tid);
    __syncthreads();

    // Fold: thread t owns bins t and t+128. Read pairs of uint16 as u32;
    // rotate start by tid so wave lanes hit distinct banks (2-way, free).
    const unsigned int* l32 = (const unsigned int*)lh;
#pragma unroll
    for (int half = 0; half < 2; half++) {
        const int bin = tid + half * TPB;
        unsigned int s = 0;
#pragma unroll 8
        for (int j = 0; j < 64; j++) {
            unsigned int w = l32[(bin << 6) + ((j + tid) & 63)];
            s += (w & 0xFFFFu) + (w >> 16);
        }
        atomicAdd(&ghist[which * NBINS + bin], s);
    }
}

// Entropy of both histograms + |diff|, all in double. One block of 256 threads.
__global__ __launch_bounds__(256) void entropy_kernel(const unsigned int* __restrict__ gh,
                                                      float* __restrict__ out) {
    __shared__ double sd[NBINS];
    const int tid = threadIdx.x;
    double e[2];

    for (int h = 0; h < 2; h++) {
        const double hv = (double)gh[h * NBINS + tid];

        sd[tid] = hv;
        __syncthreads();
        for (int o = 128; o > 0; o >>= 1) {
            if (tid < o) sd[tid] += sd[tid + o];
            __syncthreads();
        }
        const double total = sd[0];
        __syncthreads();

        const double p = hv / total + 1e-8;
        sd[tid] = -p * log(p);
        __syncthreads();
        for (int o = 128; o > 0; o >>= 1) {
            if (tid < o) sd[tid] += sd[tid + o];
            __syncthreads();
        }
        e[h] = sd[0];
        __syncthreads();
    }

    if (tid == 0) out[0] = (float)fabs(e[0] - e[1]);
}

extern "C" void kernel_launch(void* const* d_in, const int* in_sizes, int n_in,
                              void* d_out, int out_size, void* d_ws, size_t ws_size,
                              hipStream_t stream) {
    const float* pred = (const float*)d_in[0];
    const float* gt   = (const float*)d_in[1];
    const int n0 = in_sizes[0];
    const int n1 = in_sizes[1];

    unsigned int* hist = (unsigned int*)d_ws;  // [2][NBINS]
    hipMemsetAsync(d_ws, 0, 2 * NBINS * sizeof(unsigned int), stream);

    // 512 blocks per input, 128 threads each; 64 KB LDS -> 2 blocks/CU.
    const int half_blocks = 512;
    hist2_kernel<<<2 * half_blocks, TPB, 0, stream>>>(pred, gt, hist,
                                                      n0 / 4, n1 / 4, half_blocks);
    entropy_kernel<<<1, 256, 0, stream>>>(hist, (float*)d_out);
}